// Round 1
// baseline (358.892 us; speedup 1.0000x reference)
//
#include <hip/hip_runtime.h>

// bf16 fragment types for gfx950 MFMA (16x16x32: 8 bf16 in / 4 fp32 acc per lane)
using bf16x8  = __bf16 __attribute__((ext_vector_type(8)));
using floatx4 = float __attribute__((ext_vector_type(4)));

static __device__ __forceinline__ unsigned short f2b(float x) {
  unsigned u = __builtin_bit_cast(unsigned, x);
  u = (u + 0x7fffu + ((u >> 16) & 1u)) >> 16;  // RNE
  return (unsigned short)u;
}

// ---- x fp32 -> bf16, 4 elems/thread -------------------------------------
__global__ __launch_bounds__(256) void cvt_kernel(const float* __restrict__ x,
                                                  unsigned short* __restrict__ xb) {
  int i = (blockIdx.x * 256 + threadIdx.x) * 4;
  float4 v = *(const float4*)(x + i);
  unsigned long long p = (unsigned long long)f2b(v.x) |
                         ((unsigned long long)f2b(v.y) << 16) |
                         ((unsigned long long)f2b(v.z) << 32) |
                         ((unsigned long long)f2b(v.w) << 48);
  *(unsigned long long*)(xb + i) = p;
}

// ---- W fp32 [R][C] -> bf16 W^T [C][R]; dest-indexed, coalesced writes ----
__global__ __launch_bounds__(256) void transpose_kernel(const float* __restrict__ src,
                                                        unsigned short* __restrict__ dst,
                                                        int C, int logR) {
  int idx = blockIdx.x * 256 + threadIdx.x;
  int r = idx & ((1 << logR) - 1);
  int c = idx >> logR;
  dst[idx] = f2b(src[(size_t)r * C + c]);
}

// ---- generic 64x64-tile bf16 MFMA GEMM: C = A[M][Kt] * Bt[N][Kt]^T -------
// MODE 0: bf16 out at ldc   MODE 1: V scatter-transposed out   MODE 2: fp32 + bias
template <int MODE>
__global__ __launch_bounds__(256) void gemm_kernel(const unsigned short* __restrict__ A,
                                                   const unsigned short* __restrict__ Bt,
                                                   void* __restrict__ Cout,
                                                   const float* __restrict__ bias,
                                                   int Kt, int ldc) {
  __shared__ unsigned short As[64 * 40];  // pad 32->40: stride 20 words => 2-way max
  __shared__ unsigned short Bs[64 * 40];
  int tid = threadIdx.x;
  int lane = tid & 63, w = tid >> 6;
  int m16 = lane & 15, quad = lane >> 4;
  int m0 = blockIdx.y * 64, n0 = blockIdx.x * 64;
  int srow = tid >> 2, sc = (tid & 3) * 8;
  const unsigned short* aptr = A + (size_t)(m0 + srow) * Kt + sc;
  const unsigned short* bptr = Bt + (size_t)(n0 + srow) * Kt + sc;
  floatx4 acc[4] = {};
  for (int k0 = 0; k0 < Kt; k0 += 32) {
    uint4 av = *(const uint4*)(aptr + k0);
    uint4 bv = *(const uint4*)(bptr + k0);
    __syncthreads();
    *(uint4*)(&As[srow * 40 + sc]) = av;
    *(uint4*)(&Bs[srow * 40 + sc]) = bv;
    __syncthreads();
    bf16x8 af = *(const bf16x8*)(&As[(w * 16 + m16) * 40 + quad * 8]);
#pragma unroll
    for (int nt = 0; nt < 4; ++nt) {
      bf16x8 bfv = *(const bf16x8*)(&Bs[(nt * 16 + m16) * 40 + quad * 8]);
      acc[nt] = __builtin_amdgcn_mfma_f32_16x16x32_bf16(af, bfv, acc[nt], 0, 0, 0);
    }
  }
#pragma unroll
  for (int nt = 0; nt < 4; ++nt) {
#pragma unroll
    for (int r = 0; r < 4; ++r) {
      int m = m0 + w * 16 + quad * 4 + r;   // C row  (layout: row = quad*4+reg)
      int n = n0 + nt * 16 + m16;           // C col  (layout: col = lane&15)
      float v = acc[nt][r];
      if (MODE == 0) {
        ((unsigned short*)Cout)[(size_t)m * ldc + n] = f2b(v);
      } else if (MODE == 1) {
        // V^T: n = h*256+d, m = b*2048+t  ->  vt[(b*2048 + n)*2048 + t]
        int b = m >> 11, t = m & 2047;
        ((unsigned short*)Cout)[((size_t)(b * 2048 + n)) * 2048 + t] = f2b(v);
      } else {
        ((float*)Cout)[(size_t)m * ldc + n] = v + bias[n];
      }
    }
  }
}

// ---- flash attention: grid (32 q-tiles, 16 bh), 4 waves, BM=64 BN=64 d=256
__global__ __launch_bounds__(256) void attn_kernel(const unsigned short* __restrict__ qk,
                                                   const unsigned short* __restrict__ vt,
                                                   unsigned short* __restrict__ ao) {
  // union buffer: K view [64][264] (16896 sh), V^T view [256][72] (18432 sh)
  __shared__ unsigned short KV[18432];
  __shared__ unsigned short Pb[4][16 * 72];  // per-wave P, padded rows
  int tid = threadIdx.x;
  int lane = tid & 63, w = tid >> 6;
  int m16 = lane & 15, quad = lane >> 4;
  int q0 = blockIdx.x * 64;
  int bh = blockIdx.y;
  int b = bh >> 3, h = bh & 7;

  // Q fragments, resident in registers: wave w owns q-rows w*16..w*16+15
  bf16x8 qf[8];
  const unsigned short* qrow =
      qk + (size_t)(b * 2048 + q0 + w * 16 + m16) * 4096 + h * 256 + quad * 8;
#pragma unroll
  for (int c = 0; c < 8; ++c) qf[c] = *(const bf16x8*)(qrow + c * 32);

  floatx4 o[16] = {};
  float mr[4] = {-3e38f, -3e38f, -3e38f, -3e38f};
  float lr[4] = {0.f, 0.f, 0.f, 0.f};

  const unsigned short* kbase = qk + (size_t)b * 2048 * 4096 + 2048 + h * 256;
  const unsigned short* vbase = vt + (size_t)bh * 256 * 2048;
  unsigned short* pw = &Pb[w][0];

  for (int st = 0; st < 32; ++st) {
    int s0 = st * 64;
    if (st) __syncthreads();  // prior PV readers done before K overwrites buffer
    // stage K tile [64 s][256 d] (row-major, padded 264)
#pragma unroll
    for (int it = 0; it < 8; ++it) {
      int idx = it * 256 + tid;
      int sl = idx >> 5, dd = (idx & 31) * 8;
      *(uint4*)(&KV[sl * 264 + dd]) = *(const uint4*)(kbase + (size_t)(s0 + sl) * 4096 + dd);
    }
    __syncthreads();
    // S = Q K^T  (A=Q rows, B=K^T: b_frag[j] = K[s=nt*16+m16][d=c*32+quad*8+j])
    floatx4 s[4] = {};
#pragma unroll
    for (int c = 0; c < 8; ++c) {
#pragma unroll
      for (int nt = 0; nt < 4; ++nt) {
        bf16x8 kf = *(const bf16x8*)(&KV[(nt * 16 + m16) * 264 + c * 32 + quad * 8]);
        s[nt] = __builtin_amdgcn_mfma_f32_16x16x32_bf16(qf[c], kf, s[nt], 0, 0, 0);
      }
    }
    // online softmax; logits = S / 16  (k^-0.25 applied to both q and k)
    float tmax[4], rsum[4], al[4];
#pragma unroll
    for (int nt = 0; nt < 4; ++nt)
#pragma unroll
      for (int r = 0; r < 4; ++r) s[nt][r] *= 0.0625f;
#pragma unroll
    for (int r = 0; r < 4; ++r)
      tmax[r] = fmaxf(fmaxf(s[0][r], s[1][r]), fmaxf(s[2][r], s[3][r]));
#pragma unroll
    for (int off = 1; off < 16; off <<= 1)
#pragma unroll
      for (int r = 0; r < 4; ++r) tmax[r] = fmaxf(tmax[r], __shfl_xor(tmax[r], off));
#pragma unroll
    for (int r = 0; r < 4; ++r) {
      float mn = fmaxf(mr[r], tmax[r]);
      al[r] = __expf(mr[r] - mn);
      mr[r] = mn;
      rsum[r] = 0.f;
    }
#pragma unroll
    for (int nt = 0; nt < 4; ++nt)
#pragma unroll
      for (int r = 0; r < 4; ++r) {
        float p = __expf(s[nt][r] - mr[r]);
        s[nt][r] = p;
        rsum[r] += p;
      }
#pragma unroll
    for (int off = 1; off < 16; off <<= 1)
#pragma unroll
      for (int r = 0; r < 4; ++r) rsum[r] += __shfl_xor(rsum[r], off);
#pragma unroll
    for (int r = 0; r < 4; ++r) lr[r] = lr[r] * al[r] + rsum[r];
#pragma unroll
    for (int dt = 0; dt < 16; ++dt)
#pragma unroll
      for (int r = 0; r < 4; ++r) o[dt][r] *= al[r];
    // P: C-layout -> LDS (per-wave region) for A-layout reload
#pragma unroll
    for (int nt = 0; nt < 4; ++nt)
#pragma unroll
      for (int r = 0; r < 4; ++r)
        pw[(quad * 4 + r) * 72 + nt * 16 + m16] = f2b(s[nt][r]);
    __syncthreads();  // S-phase K reads done; P visible
    // stage V^T tile [256 d][64 s] (padded 72) over the same buffer
#pragma unroll
    for (int it = 0; it < 8; ++it) {
      int idx = it * 256 + tid;
      int dd = idx >> 3, sl = (idx & 7) * 8;
      *(uint4*)(&KV[dd * 72 + sl]) = *(const uint4*)(vbase + (size_t)dd * 2048 + s0 + sl);
    }
    __syncthreads();
    // O += P V   (A=P[m16][s], B: b_frag[j] = V[s=c*32+quad*8+j][d=dt*16+m16] = Vt[d][s])
    bf16x8 pa0 = *(const bf16x8*)(pw + m16 * 72 + quad * 8);
    bf16x8 pa1 = *(const bf16x8*)(pw + m16 * 72 + 32 + quad * 8);
#pragma unroll
    for (int dt = 0; dt < 16; ++dt) {
      bf16x8 v0 = *(const bf16x8*)(&KV[(dt * 16 + m16) * 72 + quad * 8]);
      o[dt] = __builtin_amdgcn_mfma_f32_16x16x32_bf16(pa0, v0, o[dt], 0, 0, 0);
    }
#pragma unroll
    for (int dt = 0; dt < 16; ++dt) {
      bf16x8 v1 = *(const bf16x8*)(&KV[(dt * 16 + m16) * 72 + 32 + quad * 8]);
      o[dt] = __builtin_amdgcn_mfma_f32_16x16x32_bf16(pa1, v1, o[dt], 0, 0, 0);
    }
  }
  float inv[4];
#pragma unroll
  for (int r = 0; r < 4; ++r) inv[r] = 1.0f / lr[r];
  unsigned short* aorow =
      ao + (size_t)(b * 2048 + q0 + w * 16 + quad * 4) * 2048 + h * 256 + m16;
#pragma unroll
  for (int dt = 0; dt < 16; ++dt)
#pragma unroll
    for (int r = 0; r < 4; ++r)
      aorow[(size_t)r * 2048 + dt * 16] = f2b(o[dt][r] * inv[r]);
}

extern "C" void kernel_launch(void* const* d_in, const int* in_sizes, int n_in,
                              void* d_out, int out_size, void* d_ws, size_t ws_size,
                              hipStream_t stream) {
  const float* x  = (const float*)d_in[0];
  const float* Wq = (const float*)d_in[1];
  const float* Wk = (const float*)d_in[2];
  const float* Wv = (const float*)d_in[3];
  const float* Wu = (const float*)d_in[4];
  const float* bu = (const float*)d_in[5];

  // ws layout (bf16 elements), total ~70 MB
  unsigned short* xb   = (unsigned short*)d_ws;      // [4096][256]
  unsigned short* wqkt = xb + 1048576;               // [4096][256]  Wq^T | Wk^T
  unsigned short* wvt  = wqkt + 1048576;             // [2048][256]  Wv^T
  unsigned short* wut  = wvt + 524288;               // [256][2048]  Wu^T
  unsigned short* qkb  = wut + 524288;               // [4096][4096] q | k
  unsigned short* vtb  = qkb + 16777216;             // [16][256][2048] V^T
  unsigned short* aob  = vtb + 8388608;              // [4096][2048] attn out

  cvt_kernel<<<1024, 256, 0, stream>>>(x, xb);
  transpose_kernel<<<2048, 256, 0, stream>>>(Wq, wqkt, 2048, 8);
  transpose_kernel<<<2048, 256, 0, stream>>>(Wk, wqkt + 524288, 2048, 8);
  transpose_kernel<<<2048, 256, 0, stream>>>(Wv, wvt, 2048, 8);
  transpose_kernel<<<2048, 256, 0, stream>>>(Wu, wut, 256, 11);
  // q,k projections: M=4096 N=4096 K=256
  gemm_kernel<0><<<dim3(64, 64), 256, 0, stream>>>(xb, wqkt, qkb, nullptr, 256, 4096);
  // v projection, transposed output: M=4096 N=2048 K=256
  gemm_kernel<1><<<dim3(32, 64), 256, 0, stream>>>(xb, wvt, vtb, nullptr, 256, 0);
  // flash attention
  attn_kernel<<<dim3(32, 16), 256, 0, stream>>>(qkb, vtb, aob);
  // output projection + bias: M=4096 N=256 K=2048, fp32 out
  gemm_kernel<2><<<dim3(4, 64), 256, 0, stream>>>(aob, wut, d_out, bu, 2048, 256);
}